// Round 6
// baseline (1051.218 us; speedup 1.0000x reference)
//
#include <hip/hip_runtime.h>

// convEP: 10-step EP relaxation, MFMA fp16 2-way-split convs (fp32-equivalent).
//   s0' = rho(fc(s1));  s1' = rho(pool(conv0(s2)) + fc^T(s0));  s2' = rho(p2 + convT(unpool(s1, idx1)))
// fp32 x = xh + 2^-12*xl' (fp16 planes, lo pre-scaled 2^12 to stay fp16-normal).
// MFMA 16x16x32_f16: A[m=l16][k=quad*8+j], B[k=quad*8+j][n=l16], C/D: col=l16, row=quad*4+reg.
// R19: convTF granularity fix (R18 hit its declared failure mode: 105KB LDS -> 1 block/CU,
// occupancy 19.5%, 50us). Split y-half -> y-QUARTER: grid (64,2,4)=512 blocks, 4 output
// rows/block, 8-row halo slab, LDS 70176 B -> 2 blocks/CU, 4 waves/SIMD (conv0F's proven
// shape). Wave owns 1 row (nt=1); total MFMA unchanged; staging halo re-read +33% (L2).
// Everything else identical to R18.

typedef _Float16 half8 __attribute__((ext_vector_type(8)));
typedef _Float16 half2v __attribute__((ext_vector_type(2)));
typedef float f32x4 __attribute__((ext_vector_type(4)));
#define MFMA_F16(A, B, C) __builtin_amdgcn_mfma_f32_16x16x32_f16((A), (B), (C), 0, 0, 0)
#define LO_SCALE 2.44140625e-4f   // 2^-12

static __device__ __forceinline__ float rho_(float x) {
  return fminf(fmaxf(x, 0.0f), 1.0f);
}
static __device__ __forceinline__ void split2(float v, _Float16& h, _Float16& l) {
  if (fabsf(v) < 6.1035156e-5f) {
    h = (_Float16)0.f;
    l = (_Float16)(v * 4096.f);
  } else {
    h = (_Float16)v;
    l = (_Float16)((v - (float)h) * 4096.f);
  }
}

// ---------------- K0: one-time weight split+transpose + s0part init ----------------
// wA0[((tap*2+kc)*128 + co)*32 + cik] = conv0w[co][kc*32+cik][tap]
// wA1[((tap*4+c )*64  + o )*32 + cpk] = conv0w[(c*32+cpk)][o][tap]
// s0part: 2 bufs x [slot 8][b 64][10]; buf0 slot0 = -fcb (so rho(sum+fcb)=0 at t=0), rest 0.
__global__ __launch_bounds__(256) void k_wprep(
    const float* __restrict__ w0, const float* __restrict__ fcb,
    _Float16* __restrict__ wA0h, _Float16* __restrict__ wA0l,
    _Float16* __restrict__ wA1h, _Float16* __restrict__ wA1l,
    float* __restrict__ s0part) {
  int i = blockIdx.x * 256 + threadIdx.x;
  if (i >= 204800) return;
  if (i < 10240) {
    int k = i - (i / 10) * 10;
    s0part[i] = (i < 640) ? -fcb[k] : 0.f;
  }
  {
    int cik = i & 31, t1 = i >> 5;
    int co = t1 & 127, t2 = t1 >> 7;
    int ck = t2 & 1, tap = t2 >> 1;
    float v = w0[(co * 64 + ck * 32 + cik) * 25 + tap];
    _Float16 h, l; split2(v, h, l);
    wA0h[i] = h; wA0l[i] = l;
  }
  {
    int cpk = i & 31, t1 = i >> 5;
    int o = t1 & 63, t2 = t1 >> 6;
    int c = t2 & 3, tap = t2 >> 2;
    float v = w0[((c * 32 + cpk) * 64 + o) * 25 + tap];
    _Float16 h, l; split2(v, h, l);
    wA1h[i] = h; wA1l[i] = l;
  }
}

// ---------------- K1: p2 = maxpool2x2(conv2d(data, conv1_w) + conv1_b) (once, fp32) ----------------
__global__ __launch_bounds__(256) void k_p2(
    const float* __restrict__ data, const float* __restrict__ w,
    const float* __restrict__ bias, float* __restrict__ p2) {
  __shared__ float ld[3][36][36];
  __shared__ float lw[16][80];
  __shared__ float lb[16];
  int b = blockIdx.x, cg = blockIdx.y, tid = threadIdx.x;
  for (int i = tid; i < 3 * 36 * 36; i += 256) {
    int ci = i / 1296, rem = i % 1296, y = rem / 36, x = rem % 36;
    int gy = y - 2, gx = x - 2;
    float v = 0.f;
    if (gy >= 0 && gy < 32 && gx >= 0 && gx < 32)
      v = data[(b * 3 + ci) * 1024 + gy * 32 + gx];
    ld[ci][y][x] = v;
  }
  for (int i = tid; i < 16 * 75; i += 256) {
    int co = i / 75, k = i % 75;
    lw[co][k] = w[(cg * 16 + co) * 75 + k];
  }
  if (tid < 16) lb[tid] = bias[cg * 16 + tid];
  __syncthreads();
  int ph = tid >> 4, pw = tid & 15;
  int ry = 2 * ph, rx = 2 * pw;
  for (int co = 0; co < 16; co++) {
    float bv = lb[co];
    float a00 = bv, a01 = bv, a10 = bv, a11 = bv;
    for (int ci = 0; ci < 3; ci++) {
#pragma unroll
      for (int ky = 0; ky < 5; ky++) {
#pragma unroll
        for (int kx = 0; kx < 5; kx++) {
          float wv = lw[co][(ci * 5 + ky) * 5 + kx];
          a00 += wv * ld[ci][ry + ky][rx + kx];
          a01 += wv * ld[ci][ry + ky][rx + kx + 1];
          a10 += wv * ld[ci][ry + ky + 1][rx + kx];
          a11 += wv * ld[ci][ry + ky + 1][rx + kx + 1];
        }
      }
    }
    float m = fmaxf(fmaxf(a00, a01), fmaxf(a10, a11));
    p2[((b * 64 + cg * 16 + co) * 16 + ph) * 16 + pw] = m;
  }
}

// ---------------- K2: conv0 (y-half) + pool/argmax + s1 update + u write + s0 FC partial ----------------
// grid (64 b, 4 cg, 2 yh) = 512 blocks, 512 thr = 8 waves = kc(2) x qh(4).
// Staging: 12-row halo slab of PRE-SPLIT packed s2pk (h|l<<16): 1 u32 load + 2 b16 LDS
// writes per element. x-halo via zero row at pos 192. LDS plane = 193 rows x 72 ci-pitch.
// s0 path: s0l = rho(sum 8 prev-slot partials + fcb); pacc[k] += s1old_j*fcw_kj reusing
// the epilogue's fcw loads; butterfly -> LDS -> 10 plain stores/block (no atomics).
__global__ __launch_bounds__(512, 4) void k_conv0F(
    const unsigned* __restrict__ s2pk,
    const _Float16* __restrict__ wA0h, const _Float16* __restrict__ wA0l,
    const float* __restrict__ b0,
    const float* __restrict__ s1old,
    const float* __restrict__ s0prevPart, float* __restrict__ s0curPart,
    const float* __restrict__ fcb,
    const float* __restrict__ fcw, float* __restrict__ s1new,
    unsigned* __restrict__ u) {
  __shared__ __align__(16) _Float16 sm[27792];   // 2 planes x [pos 193][ci 72] = 55584 B
  __shared__ float s0l[10];
  __shared__ float s0red[8][10];
  int b = blockIdx.x, cg = blockIdx.y, yh = blockIdx.z, tid = threadIdx.x;

  if (tid < 10) {   // s0_t = rho(sum of prev step's 8 slot partials + fcb); used only in epilogue
    float s = 0.f;
#pragma unroll
    for (int sl = 0; sl < 8; sl++) s += s0prevPart[(sl * 64 + b) * 10 + tid];
    s0l[tid] = rho_(s + fcb[tid]);
  }

  // stage 12-row slab: pos = ly*16+lx (ly 0..11 -> gy = yh*8-2+ly), 64 ci; pre-split packed
  for (int i = tid; i < 12288; i += 512) {
    int ci = i / 192;
    int pos = i - ci * 192;
    int ly = pos >> 4, lx = pos & 15;
    int gy = yh * 8 - 2 + ly;
    unsigned pk = 0u;
    if (gy >= 0 && gy < 16) pk = s2pk[b * 16384 + ci * 256 + gy * 16 + lx];
    half2v hv = __builtin_bit_cast(half2v, pk);
    sm[pos * 72 + ci] = hv[0];
    sm[13896 + pos * 72 + ci] = hv[1];
  }
  // zero row (pos 192) in both planes: oob B-reads land here
  if (tid < 72) {
    sm[13824 + tid] = (_Float16)0.f;           // hi plane, pos 192
    sm[13896 + 13824 + tid] = (_Float16)0.f;   // lo plane, pos 192
  }
  __syncthreads();

  int lane = tid & 63, w = tid >> 6;
  int kc = w & 1, qh = w >> 1;
  int l16 = lane & 15, quad = lane >> 4;   // l16 = x within row

  f32x4 acch[2][2], accl[2][2];   // [nt][mt]
#pragma unroll
  for (int nt = 0; nt < 2; nt++)
#pragma unroll
    for (int mt = 0; mt < 2; mt++) {
      f32x4 z; z[0] = 0.f; z[1] = 0.f; z[2] = 0.f; z[3] = 0.f;
      accl[nt][mt] = z;
      if (kc == 0) {   // bias enters exactly once (kc=0 partial)
        int cb = cg * 32 + mt * 16 + quad * 4;
        f32x4 bi; bi[0] = b0[cb]; bi[1] = b0[cb + 1]; bi[2] = b0[cb + 2]; bi[3] = b0[cb + 3];
        acch[nt][mt] = bi;
      } else {
        acch[nt][mt] = z;
      }
    }

  const int bofs = kc * 32 + quad * 8;
  const int row0 = qh * 2 * 16;
  const int Abase = (kc * 128 + cg * 32 + l16) * 32 + quad * 8;

  half8 ahc[2], alc[2];
#pragma unroll
  for (int mt = 0; mt < 2; mt++)
    ahc[mt] = *(const half8*)(wA0h + Abase + mt * 512);

  for (int tap = 0; tap < 25; tap++) {
    // lo-plane A for this tap (first use is the 2nd MFMA; LDS wait covers it)
#pragma unroll
    for (int mt = 0; mt < 2; mt++)
      alc[mt] = *(const half8*)(wA0l + Abase + tap * 8192 + mt * 512);
    // prefetch next tap's hi-plane A (double-buffer across taps)
    half8 ahn[2];
    {
      int tn = (tap < 24) ? tap + 1 : tap;
#pragma unroll
      for (int mt = 0; mt < 2; mt++)
        ahn[mt] = *(const half8*)(wA0h + Abase + tn * 8192 + mt * 512);
    }
    int ky = tap / 5, kx = tap % 5;          // loop-uniform -> scalar
    int ix = l16 + kx - 2;
    bool oob = ((unsigned)ix > 15u);
    int ptap = ky * 16 + ix;
#pragma unroll
    for (int nt = 0; nt < 2; nt++) {
      int pos = row0 + nt * 16 + ptap;       // y-pad baked into slab
      if (oob) pos = 192;                    // zero row (broadcast read)
      const _Float16* bp = sm + pos * 72 + bofs;
      half8 bh = *(const half8*)bp;
      half8 bl = *(const half8*)(bp + 13896);
#pragma unroll
      for (int mt = 0; mt < 2; mt++) {
        acch[nt][mt] = MFMA_F16(ahc[mt], bh, acch[nt][mt]);
        accl[nt][mt] = MFMA_F16(alc[mt], bh, accl[nt][mt]);
        accl[nt][mt] = MFMA_F16(ahc[mt], bl, accl[nt][mt]);
      }
    }
#pragma unroll
    for (int mt = 0; mt < 2; mt++) ahc[mt] = ahn[mt];
  }

  // kc-combine via LDS C [co 32][130] (16640 B, reuses sm)
  __syncthreads();
  float* C = (float*)sm;
  if (kc == 0) {
#pragma unroll
    for (int nt = 0; nt < 2; nt++) {
      int pos = (qh * 2 + nt) * 16 + l16;   // 0..127 within half
#pragma unroll
      for (int mt = 0; mt < 2; mt++)
#pragma unroll
        for (int r = 0; r < 4; r++)
          C[(mt * 16 + quad * 4 + r) * 130 + pos] = acch[nt][mt][r] + LO_SCALE * accl[nt][mt][r];
    }
  }
  __syncthreads();
  if (kc == 1) {
#pragma unroll
    for (int nt = 0; nt < 2; nt++) {
      int pos = (qh * 2 + nt) * 16 + l16;
#pragma unroll
      for (int mt = 0; mt < 2; mt++)
#pragma unroll
        for (int r = 0; r < 4; r++) {
          int a = (mt * 16 + quad * 4 + r) * 130 + pos;
          C[a] += acch[nt][mt][r] + LO_SCALE * accl[nt][mt][r];
        }
    }
  }
  __syncthreads();

  // epilogue: 32 co x 32 windows (pooled rows yh*4..yh*4+3)
  float pacc[10];
#pragma unroll
  for (int k = 0; k < 10; k++) pacc[k] = 0.f;

  for (int it = 0; it < 2; it++) {
    int idx = it * 512 + tid;          // 1024 = 32 co x 32 windows
    int co = idx >> 5, win = idx & 31;
    int phl = win >> 3, pw = win & 7;
    int p0 = phl * 32 + pw * 2;
    float v0 = C[co * 130 + p0];
    float v1 = C[co * 130 + p0 + 1];
    float v2 = C[co * 130 + p0 + 16];
    float v3 = C[co * 130 + p0 + 17];
    float m0 = v0; int id = 0;
    if (v1 > m0) { m0 = v1; id = 1; }
    if (v2 > m0) { m0 = v2; id = 2; }
    if (v3 > m0) { m0 = v3; id = 3; }
    int co_g = cg * 32 + co;
    int ph = yh * 4 + phl;
    int j = co_g * 64 + ph * 8 + pw;
    float sv = s1old[b * 8192 + j];
    float a = m0;
#pragma unroll
    for (int k = 0; k < 10; k++) {
      float wv = fcw[k * 8192 + j];
      a += s0l[k] * wv;
      pacc[k] += sv * wv;      // s0 FC partial (reuses the fcw load)
    }
    s1new[b * 8192 + j] = rho_(a);
    _Float16 hh, hl; split2(sv, hh, hl);
    half2v hv; hv[0] = hh; hv[1] = hl;
    unsigned pk = __builtin_bit_cast(unsigned, hv);
    int bu = (b * 256 + ph * 32 + pw * 2) * 128 + co_g;   // u32 units: [b][pos 256][cp 128]
    u[bu]        = (id == 0) ? pk : 0u;
    u[bu + 128]  = (id == 1) ? pk : 0u;
    u[bu + 2048] = (id == 2) ? pk : 0u;
    u[bu + 2176] = (id == 3) ? pk : 0u;
  }

  // s0 partial: wave butterfly -> LDS -> 10 plain stores per block (no atomics)
#pragma unroll
  for (int k = 0; k < 10; k++) {
    float v = pacc[k];
#pragma unroll
    for (int off = 32; off > 0; off >>= 1) v += __shfl_xor(v, off);
    if (lane == 0) s0red[w][k] = v;
  }
  __syncthreads();
  if (tid < 10) {
    float s = s0red[0][tid] + s0red[1][tid] + s0red[2][tid] + s0red[3][tid]
            + s0red[4][tid] + s0red[5][tid] + s0red[6][tid] + s0red[7][tid];
    s0curPart[((cg * 2 + yh) * 64 + b) * 10 + tid] = s;
  }
}

// ---------------- K3: FUSED convT: full-K GEMM + rho(p2+.)+split2 -> s2pk ----------------
// R19: y-QUARTER granularity. grid (64 b, 2 oh, 4 yq) = 512 blocks, 512 thr = 8 waves
// = kc(2: cp-half) x qh(4: one output row each). Output tile: o = oh*32..+32,
// rows y = yq*4..+4, x 0..16. K = 128 cp x 25 taps (full sum).
// Stage: 8-row u halo slab (gy = yq*4-2..+5, y-pad zeroed) -> y never oob in loop;
// x-halo via zero row at pos 128. LDS plane = [pos 129][cp 136 pitch]; lo at +17544.
// Total 70176 B -> 2 blocks/CU, 4 waves/SIMD. No P1, no atomics, no fences.
__global__ __launch_bounds__(512, 4) void k_convTF(
    const unsigned* __restrict__ u,
    const _Float16* __restrict__ wA1h, const _Float16* __restrict__ wA1l,
    const float* __restrict__ p2, unsigned* __restrict__ s2pk) {
  __shared__ __align__(16) _Float16 sm[35088];   // 2 planes x [pos 129][136] = 70176 B
  int b = blockIdx.x, oh = blockIdx.y, yq = blockIdx.z, tid = threadIdx.x;

  // stage: 8 rows x 16 x x 128 cp of packed u -> two planes
  for (int i = tid; i < 16384; i += 512) {
    int cp = i & 127, pl = i >> 7;       // pl 0..127
    int ly = pl >> 4, lx = pl & 15;
    int gy = yq * 4 - 2 + ly;
    unsigned pk = 0u;
    if ((unsigned)gy < 16u) pk = u[b * 32768 + (gy * 16 + lx) * 128 + cp];
    half2v hv = __builtin_bit_cast(half2v, pk);
    sm[pl * 136 + cp] = hv[0];
    sm[17544 + pl * 136 + cp] = hv[1];
  }
  // zero row (pos 128) both planes: 136 halfs = 68 u32 each
  if (tid < 68) {
    ((unsigned*)sm)[8704 + tid] = 0u;            // 128*136/2
    ((unsigned*)sm)[8772 + 8704 + tid] = 0u;     // + plane offset 17544/2
  }
  __syncthreads();

  int lane = tid & 63, w = tid >> 6;
  int kc = w & 1, qh = w >> 1;          // qh = output row within the quarter
  int l16 = lane & 15, quad = lane >> 4;

  f32x4 acch[2], accl[2];   // [mt]
#pragma unroll
  for (int mt = 0; mt < 2; mt++) {
    f32x4 z; z[0] = 0.f; z[1] = 0.f; z[2] = 0.f; z[3] = 0.f;
    acch[mt] = z; accl[mt] = z;
  }

  const int Aoff = (oh * 32 + l16) * 32 + quad * 8;
  const int bofs = kc * 64 + quad * 8;   // + cs*32 per iter

  half8 ahc[2], alc[2];
#pragma unroll
  for (int mt = 0; mt < 2; mt++)
    ahc[mt] = *(const half8*)(wA1h + (kc * 2) * 2048 + Aoff + mt * 512);

  for (int it = 0; it < 50; it++) {
    int tap = it >> 1, cs = it & 1;
    int Ab = (tap * 4 + kc * 2 + cs) * 2048;
#pragma unroll
    for (int mt = 0; mt < 2; mt++)
      alc[mt] = *(const half8*)(wA1l + Ab + Aoff + mt * 512);
    half8 ahn[2];
    {
      int itn = (it < 49) ? it + 1 : it;
      int Abn = ((itn >> 1) * 4 + kc * 2 + (itn & 1)) * 2048;
#pragma unroll
      for (int mt = 0; mt < 2; mt++)
        ahn[mt] = *(const half8*)(wA1h + Abn + Aoff + mt * 512);
    }
    int ky = tap / 5, kx = tap - ky * 5;
    int ix = l16 + 2 - kx;
    bool oob = ((unsigned)ix > 15u);
    int pos = (qh + 4 - ky) * 16 + ix;   // slab row qh+4-ky in 0..7 (halo staged)
    if (oob) pos = 128;                  // zero row (broadcast read)
    const _Float16* bp = sm + pos * 136 + bofs + cs * 32;
    half8 bh = *(const half8*)bp;
    half8 bl = *(const half8*)(bp + 17544);
#pragma unroll
    for (int mt = 0; mt < 2; mt++) {
      acch[mt] = MFMA_F16(ahc[mt], bh, acch[mt]);
      accl[mt] = MFMA_F16(alc[mt], bh, accl[mt]);
      accl[mt] = MFMA_F16(ahc[mt], bl, accl[mt]);
    }
#pragma unroll
    for (int mt = 0; mt < 2; mt++) ahc[mt] = ahn[mt];
  }

  // kc-combine via LDS C [o 32][66] (8448 B, reuses sm)
  __syncthreads();
  float* C = (float*)sm;
  if (kc == 0) {
    int pos = qh * 16 + l16;   // 0..63 (row qh, x l16)
#pragma unroll
    for (int mt = 0; mt < 2; mt++)
#pragma unroll
      for (int r = 0; r < 4; r++)
        C[(mt * 16 + quad * 4 + r) * 66 + pos] = acch[mt][r] + LO_SCALE * accl[mt][r];
  }
  __syncthreads();
  if (kc == 1) {
    int pos = qh * 16 + l16;
#pragma unroll
    for (int mt = 0; mt < 2; mt++)
#pragma unroll
      for (int r = 0; r < 4; r++) {
        int a = (mt * 16 + quad * 4 + r) * 66 + pos;
        C[a] += acch[mt][r] + LO_SCALE * accl[mt][r];
      }
  }
  __syncthreads();

  // epilogue: s2 = rho(p2 + C), split2, pack -> s2pk (32 o x 64 pos)
  int gbase = b * 16384 + oh * 8192 + yq * 64;
  for (int m = tid; m < 2048; m += 512) {
    int o = m >> 6, pos = m & 63;        // pos = row(2b)*16 + x
    int gi = gbase + o * 256 + pos;
    float v = rho_(p2[gi] + C[o * 66 + pos]);
    _Float16 h, l; split2(v, h, l);
    half2v hv; hv[0] = h; hv[1] = l;
    s2pk[gi] = __builtin_bit_cast(unsigned, hv);
  }
}

// ---------------- K3b: s2 unpack + s1 copy + s0 finalize (t=6 snapshot, t=9 final) ----------------
// blocks 0..1023: s2 = unpack(s2pk) (+ first 640 lanes: s0 = rho(sum 8 partials + fcb));
// blocks 1024..1535: s1 float4 copy.
__global__ __launch_bounds__(256) void k_cTcomb(
    const unsigned* __restrict__ s2pk, float* __restrict__ out_s2,
    const float* __restrict__ s1src, float* __restrict__ out_s1,
    const float* __restrict__ s0part, const float* __restrict__ fcb,
    float* __restrict__ out_s0) {
  int blk = blockIdx.x, tid = threadIdx.x;
  if (blk < 1024) {
    int i = blk * 256 + tid;   // over 262144 uint4s
    uint4 pk = ((const uint4*)s2pk)[i];
    float4 o;
    half2v h0 = __builtin_bit_cast(half2v, pk.x);
    half2v h1 = __builtin_bit_cast(half2v, pk.y);
    half2v h2 = __builtin_bit_cast(half2v, pk.z);
    half2v h3 = __builtin_bit_cast(half2v, pk.w);
    o.x = (float)h0[0] + LO_SCALE * (float)h0[1];
    o.y = (float)h1[0] + LO_SCALE * (float)h1[1];
    o.z = (float)h2[0] + LO_SCALE * (float)h2[1];
    o.w = (float)h3[0] + LO_SCALE * (float)h3[1];
    ((float4*)out_s2)[i] = o;
    if (i < 640) {
      int bb = i / 10, k = i - bb * 10;
      float s = 0.f;
#pragma unroll
      for (int sl = 0; sl < 8; sl++) s += s0part[(sl * 64 + bb) * 10 + k];
      out_s0[i] = rho_(s + fcb[k]);
    }
  } else {
    int i2 = (blk - 1024) * 256 + tid;   // over 131072 float4s (2 MB)
    ((float4*)out_s1)[i2] = ((const float4*)s1src)[i2];
  }
}

extern "C" void kernel_launch(void* const* d_in, const int* in_sizes, int n_in,
                              void* d_out, int out_size, void* d_ws, size_t ws_size,
                              hipStream_t stream) {
  const float* data   = (const float*)d_in[0];
  const float* s0init = (const float*)d_in[1];   // zeros
  const float* s1init = (const float*)d_in[2];   // zeros
  const float* s2init = (const float*)d_in[3];   // zeros (t=0 conv0 input)
  const float* conv0w = (const float*)d_in[4];
  const float* conv0b = (const float*)d_in[5];
  const float* conv1w = (const float*)d_in[6];
  const float* conv1b = (const float*)d_in[7];
  const float* fcw    = (const float*)d_in[8];
  const float* fcb    = (const float*)d_in[9];
  (void)s0init; (void)s2init;

  // workspace (~22 MB of 256 MB)
  float* p = (float*)d_ws;
  float* s0part = p;                         p += 10240;     // 2 bufs x [slot 8][b 64][10]
  float* s1buf[2] = {p, p + 524288};         p += 1048576;
  float* p2 = p;                             p += 1048576;
  unsigned* u = (unsigned*)p;                p += 2097152;   // packed hi|lo [b][pos 256][cp 128]
  unsigned* s2pk = (unsigned*)p;             p += 1048576;   // packed split s2 [b][ci 64][16][16]
  _Float16* hq = (_Float16*)p;
  _Float16* wA0h = hq;                       hq += 204800;
  _Float16* wA0l = hq;                       hq += 204800;
  _Float16* wA1h = hq;                       hq += 204800;
  _Float16* wA1l = hq;                       hq += 204800;

  hipMemsetAsync(s2pk, 0, 1048576 * sizeof(unsigned), stream);   // t=0: s2 = 0 (packed split(0)=0)
  k_wprep<<<800, 256, 0, stream>>>(conv0w, fcb, wA0h, wA0l, wA1h, wA1l, s0part);
  k_p2<<<dim3(64, 4), 256, 0, stream>>>(data, conv1w, conv1b, p2);

  const float* s1o = s1init;
  float* outp = (float*)d_out;

  for (int t = 0; t < 10; t++) {
    int nb = t & 1;
    float* s1w = s1buf[nb];

    // conv0(s2_t from packed s2pk) + pool/argmax; s1_new = rho(p1 + fc^T(s0_t));
    // u = split(unpool(s1_old, idx)); s0 FC partials -> s0part buf[(t+1)&1]
    k_conv0F<<<dim3(64, 4, 2), 512, 0, stream>>>(s2pk,
                                                 wA0h, wA0l, conv0b,
                                                 s1o,
                                                 s0part + (t & 1) * 5120,
                                                 s0part + ((t + 1) & 1) * 5120,
                                                 fcb, fcw, s1w, u);
    // fused convT (y-quarter): full-K sum + rho(p2+.)+split2 -> s2pk
    k_convTF<<<dim3(64, 2, 4), 512, 0, stream>>>(u, wA1h, wA1l, p2, s2pk);

    s1o = s1w;

    if (t == 6) {   // PRED_T snapshot: s0_7, s1_7, s2_7 = unpack(s2pk) -> d_out directly
      k_cTcomb<<<1536, 256, 0, stream>>>(s2pk, outp + 2098432,
                                         s1o, outp + 1574144,
                                         s0part + 5120, fcb, outp + 1573504);
    }
  }

  // final states: s0_10 (partials in buf[0]), s1_10, s2_10 -> d_out
  k_cTcomb<<<1536, 256, 0, stream>>>(s2pk, outp + 524928,
                                     s1o, outp + 640,
                                     s0part, fcb, outp + 0);
}

// Round 7
// 740.958 us; speedup vs baseline: 1.4187x; 1.4187x over previous
//
#include <hip/hip_runtime.h>

// convEP: 10-step EP relaxation, MFMA fp16 2-way-split convs (fp32-equivalent).
//   s0' = rho(fc(s1));  s1' = rho(pool(conv0(s2)) + fc^T(s0));  s2' = rho(p2 + convT(unpool(s1, idx1)))
// fp32 x = xh + 2^-12*xl' (fp16 planes, lo pre-scaled 2^12 to stay fp16-normal).
// MFMA 16x16x32_f16: A[m=l16][k=quad*8+j], B[k=quad*8+j][n=l16], C/D: col=l16, row=quad*4+reg.
// R20: convTF wave redecomposition. R19's 3-MFMA-per-A-load-group exposed ~200cy L2 latency
// per iter (50 iters) -> 61.6us @ MfmaUtil 12%. Fix: 8 waves = kc(2 cp-half) x tg(4 tap-group
// {7,6,6,6}); wave computes ALL 4 rows (nt=4) of its tap subset -> 24 MFMAs per A-group
// (R16-convTg's proven ratio), 12-14 iters, A double-buffered both planes. 8 partials
// combine via per-wave LDS C-slices [8][32][66] (67.6KB in the 70KB slab, one parallel
// write phase) -> sum8 + rho(p2+.) + split2 -> s2pk. fp32 sum reorder only (~1e-7, safe:
// R15's nondeterministic atomic order gave identical absmax). LDS 70176B, 2 blk/CU.

typedef _Float16 half8 __attribute__((ext_vector_type(8)));
typedef _Float16 half2v __attribute__((ext_vector_type(2)));
typedef float f32x4 __attribute__((ext_vector_type(4)));
#define MFMA_F16(A, B, C) __builtin_amdgcn_mfma_f32_16x16x32_f16((A), (B), (C), 0, 0, 0)
#define LO_SCALE 2.44140625e-4f   // 2^-12

static __device__ __forceinline__ float rho_(float x) {
  return fminf(fmaxf(x, 0.0f), 1.0f);
}
static __device__ __forceinline__ void split2(float v, _Float16& h, _Float16& l) {
  if (fabsf(v) < 6.1035156e-5f) {
    h = (_Float16)0.f;
    l = (_Float16)(v * 4096.f);
  } else {
    h = (_Float16)v;
    l = (_Float16)((v - (float)h) * 4096.f);
  }
}

// ---------------- K0: one-time weight split+transpose + s0part init ----------------
// wA0[((tap*2+kc)*128 + co)*32 + cik] = conv0w[co][kc*32+cik][tap]
// wA1[((tap*4+c )*64  + o )*32 + cpk] = conv0w[(c*32+cpk)][o][tap]
// s0part: 2 bufs x [slot 8][b 64][10]; buf0 slot0 = -fcb (so rho(sum+fcb)=0 at t=0), rest 0.
__global__ __launch_bounds__(256) void k_wprep(
    const float* __restrict__ w0, const float* __restrict__ fcb,
    _Float16* __restrict__ wA0h, _Float16* __restrict__ wA0l,
    _Float16* __restrict__ wA1h, _Float16* __restrict__ wA1l,
    float* __restrict__ s0part) {
  int i = blockIdx.x * 256 + threadIdx.x;
  if (i >= 204800) return;
  if (i < 10240) {
    int k = i - (i / 10) * 10;
    s0part[i] = (i < 640) ? -fcb[k] : 0.f;
  }
  {
    int cik = i & 31, t1 = i >> 5;
    int co = t1 & 127, t2 = t1 >> 7;
    int ck = t2 & 1, tap = t2 >> 1;
    float v = w0[(co * 64 + ck * 32 + cik) * 25 + tap];
    _Float16 h, l; split2(v, h, l);
    wA0h[i] = h; wA0l[i] = l;
  }
  {
    int cpk = i & 31, t1 = i >> 5;
    int o = t1 & 63, t2 = t1 >> 6;
    int c = t2 & 3, tap = t2 >> 2;
    float v = w0[((c * 32 + cpk) * 64 + o) * 25 + tap];
    _Float16 h, l; split2(v, h, l);
    wA1h[i] = h; wA1l[i] = l;
  }
}

// ---------------- K1: p2 = maxpool2x2(conv2d(data, conv1_w) + conv1_b) (once, fp32) ----------------
__global__ __launch_bounds__(256) void k_p2(
    const float* __restrict__ data, const float* __restrict__ w,
    const float* __restrict__ bias, float* __restrict__ p2) {
  __shared__ float ld[3][36][36];
  __shared__ float lw[16][80];
  __shared__ float lb[16];
  int b = blockIdx.x, cg = blockIdx.y, tid = threadIdx.x;
  for (int i = tid; i < 3 * 36 * 36; i += 256) {
    int ci = i / 1296, rem = i % 1296, y = rem / 36, x = rem % 36;
    int gy = y - 2, gx = x - 2;
    float v = 0.f;
    if (gy >= 0 && gy < 32 && gx >= 0 && gx < 32)
      v = data[(b * 3 + ci) * 1024 + gy * 32 + gx];
    ld[ci][y][x] = v;
  }
  for (int i = tid; i < 16 * 75; i += 256) {
    int co = i / 75, k = i % 75;
    lw[co][k] = w[(cg * 16 + co) * 75 + k];
  }
  if (tid < 16) lb[tid] = bias[cg * 16 + tid];
  __syncthreads();
  int ph = tid >> 4, pw = tid & 15;
  int ry = 2 * ph, rx = 2 * pw;
  for (int co = 0; co < 16; co++) {
    float bv = lb[co];
    float a00 = bv, a01 = bv, a10 = bv, a11 = bv;
    for (int ci = 0; ci < 3; ci++) {
#pragma unroll
      for (int ky = 0; ky < 5; ky++) {
#pragma unroll
        for (int kx = 0; kx < 5; kx++) {
          float wv = lw[co][(ci * 5 + ky) * 5 + kx];
          a00 += wv * ld[ci][ry + ky][rx + kx];
          a01 += wv * ld[ci][ry + ky][rx + kx + 1];
          a10 += wv * ld[ci][ry + ky + 1][rx + kx];
          a11 += wv * ld[ci][ry + ky + 1][rx + kx + 1];
        }
      }
    }
    float m = fmaxf(fmaxf(a00, a01), fmaxf(a10, a11));
    p2[((b * 64 + cg * 16 + co) * 16 + ph) * 16 + pw] = m;
  }
}

// ---------------- K2: conv0 (y-half) + pool/argmax + s1 update + u write + s0 FC partial ----------------
// grid (64 b, 4 cg, 2 yh) = 512 blocks, 512 thr = 8 waves = kc(2) x qh(4).
// Staging: 12-row halo slab of PRE-SPLIT packed s2pk (h|l<<16): 1 u32 load + 2 b16 LDS
// writes per element. x-halo via zero row at pos 192. LDS plane = 193 rows x 72 ci-pitch.
// s0 path: s0l = rho(sum 8 prev-slot partials + fcb); pacc[k] += s1old_j*fcw_kj reusing
// the epilogue's fcw loads; butterfly -> LDS -> 10 plain stores/block (no atomics).
__global__ __launch_bounds__(512, 4) void k_conv0F(
    const unsigned* __restrict__ s2pk,
    const _Float16* __restrict__ wA0h, const _Float16* __restrict__ wA0l,
    const float* __restrict__ b0,
    const float* __restrict__ s1old,
    const float* __restrict__ s0prevPart, float* __restrict__ s0curPart,
    const float* __restrict__ fcb,
    const float* __restrict__ fcw, float* __restrict__ s1new,
    unsigned* __restrict__ u) {
  __shared__ __align__(16) _Float16 sm[27792];   // 2 planes x [pos 193][ci 72] = 55584 B
  __shared__ float s0l[10];
  __shared__ float s0red[8][10];
  int b = blockIdx.x, cg = blockIdx.y, yh = blockIdx.z, tid = threadIdx.x;

  if (tid < 10) {   // s0_t = rho(sum of prev step's 8 slot partials + fcb); used only in epilogue
    float s = 0.f;
#pragma unroll
    for (int sl = 0; sl < 8; sl++) s += s0prevPart[(sl * 64 + b) * 10 + tid];
    s0l[tid] = rho_(s + fcb[tid]);
  }

  // stage 12-row slab: pos = ly*16+lx (ly 0..11 -> gy = yh*8-2+ly), 64 ci; pre-split packed
  for (int i = tid; i < 12288; i += 512) {
    int ci = i / 192;
    int pos = i - ci * 192;
    int ly = pos >> 4, lx = pos & 15;
    int gy = yh * 8 - 2 + ly;
    unsigned pk = 0u;
    if (gy >= 0 && gy < 16) pk = s2pk[b * 16384 + ci * 256 + gy * 16 + lx];
    half2v hv = __builtin_bit_cast(half2v, pk);
    sm[pos * 72 + ci] = hv[0];
    sm[13896 + pos * 72 + ci] = hv[1];
  }
  // zero row (pos 192) in both planes: oob B-reads land here
  if (tid < 72) {
    sm[13824 + tid] = (_Float16)0.f;           // hi plane, pos 192
    sm[13896 + 13824 + tid] = (_Float16)0.f;   // lo plane, pos 192
  }
  __syncthreads();

  int lane = tid & 63, w = tid >> 6;
  int kc = w & 1, qh = w >> 1;
  int l16 = lane & 15, quad = lane >> 4;   // l16 = x within row

  f32x4 acch[2][2], accl[2][2];   // [nt][mt]
#pragma unroll
  for (int nt = 0; nt < 2; nt++)
#pragma unroll
    for (int mt = 0; mt < 2; mt++) {
      f32x4 z; z[0] = 0.f; z[1] = 0.f; z[2] = 0.f; z[3] = 0.f;
      accl[nt][mt] = z;
      if (kc == 0) {   // bias enters exactly once (kc=0 partial)
        int cb = cg * 32 + mt * 16 + quad * 4;
        f32x4 bi; bi[0] = b0[cb]; bi[1] = b0[cb + 1]; bi[2] = b0[cb + 2]; bi[3] = b0[cb + 3];
        acch[nt][mt] = bi;
      } else {
        acch[nt][mt] = z;
      }
    }

  const int bofs = kc * 32 + quad * 8;
  const int row0 = qh * 2 * 16;
  const int Abase = (kc * 128 + cg * 32 + l16) * 32 + quad * 8;

  half8 ahc[2], alc[2];
#pragma unroll
  for (int mt = 0; mt < 2; mt++)
    ahc[mt] = *(const half8*)(wA0h + Abase + mt * 512);

  for (int tap = 0; tap < 25; tap++) {
    // lo-plane A for this tap (first use is the 2nd MFMA; LDS wait covers it)
#pragma unroll
    for (int mt = 0; mt < 2; mt++)
      alc[mt] = *(const half8*)(wA0l + Abase + tap * 8192 + mt * 512);
    // prefetch next tap's hi-plane A (double-buffer across taps)
    half8 ahn[2];
    {
      int tn = (tap < 24) ? tap + 1 : tap;
#pragma unroll
      for (int mt = 0; mt < 2; mt++)
        ahn[mt] = *(const half8*)(wA0h + Abase + tn * 8192 + mt * 512);
    }
    int ky = tap / 5, kx = tap % 5;          // loop-uniform -> scalar
    int ix = l16 + kx - 2;
    bool oob = ((unsigned)ix > 15u);
    int ptap = ky * 16 + ix;
#pragma unroll
    for (int nt = 0; nt < 2; nt++) {
      int pos = row0 + nt * 16 + ptap;       // y-pad baked into slab
      if (oob) pos = 192;                    // zero row (broadcast read)
      const _Float16* bp = sm + pos * 72 + bofs;
      half8 bh = *(const half8*)bp;
      half8 bl = *(const half8*)(bp + 13896);
#pragma unroll
      for (int mt = 0; mt < 2; mt++) {
        acch[nt][mt] = MFMA_F16(ahc[mt], bh, acch[nt][mt]);
        accl[nt][mt] = MFMA_F16(alc[mt], bh, accl[nt][mt]);
        accl[nt][mt] = MFMA_F16(ahc[mt], bl, accl[nt][mt]);
      }
    }
#pragma unroll
    for (int mt = 0; mt < 2; mt++) ahc[mt] = ahn[mt];
  }

  // kc-combine via LDS C [co 32][130] (16640 B, reuses sm)
  __syncthreads();
  float* C = (float*)sm;
  if (kc == 0) {
#pragma unroll
    for (int nt = 0; nt < 2; nt++) {
      int pos = (qh * 2 + nt) * 16 + l16;   // 0..127 within half
#pragma unroll
      for (int mt = 0; mt < 2; mt++)
#pragma unroll
        for (int r = 0; r < 4; r++)
          C[(mt * 16 + quad * 4 + r) * 130 + pos] = acch[nt][mt][r] + LO_SCALE * accl[nt][mt][r];
    }
  }
  __syncthreads();
  if (kc == 1) {
#pragma unroll
    for (int nt = 0; nt < 2; nt++) {
      int pos = (qh * 2 + nt) * 16 + l16;
#pragma unroll
      for (int mt = 0; mt < 2; mt++)
#pragma unroll
        for (int r = 0; r < 4; r++) {
          int a = (mt * 16 + quad * 4 + r) * 130 + pos;
          C[a] += acch[nt][mt][r] + LO_SCALE * accl[nt][mt][r];
        }
    }
  }
  __syncthreads();

  // epilogue: 32 co x 32 windows (pooled rows yh*4..yh*4+3)
  float pacc[10];
#pragma unroll
  for (int k = 0; k < 10; k++) pacc[k] = 0.f;

  for (int it = 0; it < 2; it++) {
    int idx = it * 512 + tid;          // 1024 = 32 co x 32 windows
    int co = idx >> 5, win = idx & 31;
    int phl = win >> 3, pw = win & 7;
    int p0 = phl * 32 + pw * 2;
    float v0 = C[co * 130 + p0];
    float v1 = C[co * 130 + p0 + 1];
    float v2 = C[co * 130 + p0 + 16];
    float v3 = C[co * 130 + p0 + 17];
    float m0 = v0; int id = 0;
    if (v1 > m0) { m0 = v1; id = 1; }
    if (v2 > m0) { m0 = v2; id = 2; }
    if (v3 > m0) { m0 = v3; id = 3; }
    int co_g = cg * 32 + co;
    int ph = yh * 4 + phl;
    int j = co_g * 64 + ph * 8 + pw;
    float sv = s1old[b * 8192 + j];
    float a = m0;
#pragma unroll
    for (int k = 0; k < 10; k++) {
      float wv = fcw[k * 8192 + j];
      a += s0l[k] * wv;
      pacc[k] += sv * wv;      // s0 FC partial (reuses the fcw load)
    }
    s1new[b * 8192 + j] = rho_(a);
    _Float16 hh, hl; split2(sv, hh, hl);
    half2v hv; hv[0] = hh; hv[1] = hl;
    unsigned pk = __builtin_bit_cast(unsigned, hv);
    int bu = (b * 256 + ph * 32 + pw * 2) * 128 + co_g;   // u32 units: [b][pos 256][cp 128]
    u[bu]        = (id == 0) ? pk : 0u;
    u[bu + 128]  = (id == 1) ? pk : 0u;
    u[bu + 2048] = (id == 2) ? pk : 0u;
    u[bu + 2176] = (id == 3) ? pk : 0u;
  }

  // s0 partial: wave butterfly -> LDS -> 10 plain stores per block (no atomics)
#pragma unroll
  for (int k = 0; k < 10; k++) {
    float v = pacc[k];
#pragma unroll
    for (int off = 32; off > 0; off >>= 1) v += __shfl_xor(v, off);
    if (lane == 0) s0red[w][k] = v;
  }
  __syncthreads();
  if (tid < 10) {
    float s = s0red[0][tid] + s0red[1][tid] + s0red[2][tid] + s0red[3][tid]
            + s0red[4][tid] + s0red[5][tid] + s0red[6][tid] + s0red[7][tid];
    s0curPart[((cg * 2 + yh) * 64 + b) * 10 + tid] = s;
  }
}

// ---------------- K3: FUSED convT: full-K GEMM + rho(p2+.)+split2 -> s2pk ----------------
// R20: wave = kc(2 cp-half) x tg(4 tap-group {7,6,6,6}); nt=4 rows (whole y-quarter).
// Per iter (tap,cs): 4 A-loads (double-buffered both planes) -> 24 MFMAs. 12-14 iters.
// grid (64 b, 2 oh, 4 yq) = 512 blocks. Stage: 8-row u halo slab, x-zero-row at pos 128.
// LDS 70176 B -> 2 blk/CU. 8 partials -> per-wave C-slices [8][32][66] (67.6KB, one
// parallel write) -> sum8 + rho(p2+.) + split2 -> s2pk. No P1, no atomics, no fences.
__global__ __launch_bounds__(512, 4) void k_convTF(
    const unsigned* __restrict__ u,
    const _Float16* __restrict__ wA1h, const _Float16* __restrict__ wA1l,
    const float* __restrict__ p2, unsigned* __restrict__ s2pk) {
  __shared__ __align__(16) _Float16 sm[35088];   // 2 planes x [pos 129][136] = 70176 B
  int b = blockIdx.x, oh = blockIdx.y, yq = blockIdx.z, tid = threadIdx.x;

  // stage: 8 rows x 16 x x 128 cp of packed u -> two planes
  for (int i = tid; i < 16384; i += 512) {
    int cp = i & 127, pl = i >> 7;       // pl 0..127
    int ly = pl >> 4, lx = pl & 15;
    int gy = yq * 4 - 2 + ly;
    unsigned pk = 0u;
    if ((unsigned)gy < 16u) pk = u[b * 32768 + (gy * 16 + lx) * 128 + cp];
    half2v hv = __builtin_bit_cast(half2v, pk);
    sm[pl * 136 + cp] = hv[0];
    sm[17544 + pl * 136 + cp] = hv[1];
  }
  // zero row (pos 128) both planes: 136 halfs = 68 u32 each
  if (tid < 68) {
    ((unsigned*)sm)[8704 + tid] = 0u;            // 128*136/2
    ((unsigned*)sm)[8772 + 8704 + tid] = 0u;     // + plane offset 17544/2
  }
  __syncthreads();

  int lane = tid & 63, w = tid >> 6;
  int kc = w & 1, tg = w >> 1;
  int l16 = lane & 15, quad = lane >> 4;

  f32x4 acch[4][2], accl[4][2];   // [nt: 4 rows][mt]
#pragma unroll
  for (int nt = 0; nt < 4; nt++)
#pragma unroll
    for (int mt = 0; mt < 2; mt++) {
      f32x4 z; z[0] = 0.f; z[1] = 0.f; z[2] = 0.f; z[3] = 0.f;
      acch[nt][mt] = z; accl[nt][mt] = z;
    }

  const int Aoff = (oh * 32 + l16) * 32 + quad * 8;
  const int bofs = kc * 64 + quad * 8;
  const int tapLo = (tg == 0) ? 0 : 1 + 6 * tg;       // {0,7,13,19}
  const int itBeg = tapLo * 2;
  const int itEnd = (tapLo + ((tg == 0) ? 7 : 6)) * 2;

  half8 ahc[2], alc[2];
  {
    int Ab = (tapLo * 4 + kc * 2) * 2048;
#pragma unroll
    for (int mt = 0; mt < 2; mt++) {
      ahc[mt] = *(const half8*)(wA1h + Ab + Aoff + mt * 512);
      alc[mt] = *(const half8*)(wA1l + Ab + Aoff + mt * 512);
    }
  }

  for (int it = itBeg; it < itEnd; it++) {
    // prefetch next iter's A, both planes (full double-buffer)
    half8 ahn[2], aln[2];
    {
      int itn = (it + 1 < itEnd) ? it + 1 : it;
      int Abn = ((itn >> 1) * 4 + kc * 2 + (itn & 1)) * 2048;
#pragma unroll
      for (int mt = 0; mt < 2; mt++) {
        ahn[mt] = *(const half8*)(wA1h + Abn + Aoff + mt * 512);
        aln[mt] = *(const half8*)(wA1l + Abn + Aoff + mt * 512);
      }
    }
    int tap = it >> 1, cs = it & 1;
    int ky = tap / 5, kx = tap - ky * 5;
    int ix = l16 + 2 - kx;
    bool oob = ((unsigned)ix > 15u);
#pragma unroll
    for (int nt = 0; nt < 4; nt++) {
      int pos = (nt + 4 - ky) * 16 + ix;   // slab row in 0..7 (y-halo staged, never oob)
      if (oob) pos = 128;                  // zero row (broadcast read)
      const _Float16* bp = sm + pos * 136 + bofs + cs * 32;
      half8 bh = *(const half8*)bp;
      half8 bl = *(const half8*)(bp + 17544);
#pragma unroll
      for (int mt = 0; mt < 2; mt++) {
        acch[nt][mt] = MFMA_F16(ahc[mt], bh, acch[nt][mt]);
        accl[nt][mt] = MFMA_F16(alc[mt], bh, accl[nt][mt]);
        accl[nt][mt] = MFMA_F16(ahc[mt], bl, accl[nt][mt]);
      }
    }
#pragma unroll
    for (int mt = 0; mt < 2; mt++) { ahc[mt] = ahn[mt]; alc[mt] = aln[mt]; }
  }

  // combine: per-wave C-slice [w][o 32][66] (8*2112 floats = 67584 B, reuses slab)
  __syncthreads();
  float* C = (float*)sm;
  float* Cw = C + w * 2112;
#pragma unroll
  for (int nt = 0; nt < 4; nt++) {
    int pos = nt * 16 + l16;
#pragma unroll
    for (int mt = 0; mt < 2; mt++)
#pragma unroll
      for (int r = 0; r < 4; r++)
        Cw[(mt * 16 + quad * 4 + r) * 66 + pos] = acch[nt][mt][r] + LO_SCALE * accl[nt][mt][r];
  }
  __syncthreads();

  // epilogue: s2 = rho(p2 + sum8), split2, pack -> s2pk (32 o x 64 pos)
  int gbase = b * 16384 + oh * 8192 + yq * 64;
  for (int m = tid; m < 2048; m += 512) {
    int o = m >> 6, pos = m & 63;        // pos = row*16 + x
    int ci = o * 66 + pos;
    float s = C[ci]          + C[ci + 2112]  + C[ci + 4224]  + C[ci + 6336]
            + C[ci + 8448]   + C[ci + 10560] + C[ci + 12672] + C[ci + 14784];
    int gi = gbase + o * 256 + pos;
    float v = rho_(p2[gi] + s);
    _Float16 h, l; split2(v, h, l);
    half2v hv; hv[0] = h; hv[1] = l;
    s2pk[gi] = __builtin_bit_cast(unsigned, hv);
  }
}

// ---------------- K3b: s2 unpack + s1 copy + s0 finalize (t=6 snapshot, t=9 final) ----------------
// blocks 0..1023: s2 = unpack(s2pk) (+ first 640 lanes: s0 = rho(sum 8 partials + fcb));
// blocks 1024..1535: s1 float4 copy.
__global__ __launch_bounds__(256) void k_cTcomb(
    const unsigned* __restrict__ s2pk, float* __restrict__ out_s2,
    const float* __restrict__ s1src, float* __restrict__ out_s1,
    const float* __restrict__ s0part, const float* __restrict__ fcb,
    float* __restrict__ out_s0) {
  int blk = blockIdx.x, tid = threadIdx.x;
  if (blk < 1024) {
    int i = blk * 256 + tid;   // over 262144 uint4s
    uint4 pk = ((const uint4*)s2pk)[i];
    float4 o;
    half2v h0 = __builtin_bit_cast(half2v, pk.x);
    half2v h1 = __builtin_bit_cast(half2v, pk.y);
    half2v h2 = __builtin_bit_cast(half2v, pk.z);
    half2v h3 = __builtin_bit_cast(half2v, pk.w);
    o.x = (float)h0[0] + LO_SCALE * (float)h0[1];
    o.y = (float)h1[0] + LO_SCALE * (float)h1[1];
    o.z = (float)h2[0] + LO_SCALE * (float)h2[1];
    o.w = (float)h3[0] + LO_SCALE * (float)h3[1];
    ((float4*)out_s2)[i] = o;
    if (i < 640) {
      int bb = i / 10, k = i - bb * 10;
      float s = 0.f;
#pragma unroll
      for (int sl = 0; sl < 8; sl++) s += s0part[(sl * 64 + bb) * 10 + k];
      out_s0[i] = rho_(s + fcb[k]);
    }
  } else {
    int i2 = (blk - 1024) * 256 + tid;   // over 131072 float4s (2 MB)
    ((float4*)out_s1)[i2] = ((const float4*)s1src)[i2];
  }
}

extern "C" void kernel_launch(void* const* d_in, const int* in_sizes, int n_in,
                              void* d_out, int out_size, void* d_ws, size_t ws_size,
                              hipStream_t stream) {
  const float* data   = (const float*)d_in[0];
  const float* s0init = (const float*)d_in[1];   // zeros
  const float* s1init = (const float*)d_in[2];   // zeros
  const float* s2init = (const float*)d_in[3];   // zeros (t=0 conv0 input)
  const float* conv0w = (const float*)d_in[4];
  const float* conv0b = (const float*)d_in[5];
  const float* conv1w = (const float*)d_in[6];
  const float* conv1b = (const float*)d_in[7];
  const float* fcw    = (const float*)d_in[8];
  const float* fcb    = (const float*)d_in[9];
  (void)s0init; (void)s2init;

  // workspace (~22 MB of 256 MB)
  float* p = (float*)d_ws;
  float* s0part = p;                         p += 10240;     // 2 bufs x [slot 8][b 64][10]
  float* s1buf[2] = {p, p + 524288};         p += 1048576;
  float* p2 = p;                             p += 1048576;
  unsigned* u = (unsigned*)p;                p += 2097152;   // packed hi|lo [b][pos 256][cp 128]
  unsigned* s2pk = (unsigned*)p;             p += 1048576;   // packed split s2 [b][ci 64][16][16]
  _Float16* hq = (_Float16*)p;
  _Float16* wA0h = hq;                       hq += 204800;
  _Float16* wA0l = hq;                       hq += 204800;
  _Float16* wA1h = hq;                       hq += 204800;
  _Float16* wA1l = hq;                       hq += 204800;

  hipMemsetAsync(s2pk, 0, 1048576 * sizeof(unsigned), stream);   // t=0: s2 = 0 (packed split(0)=0)
  k_wprep<<<800, 256, 0, stream>>>(conv0w, fcb, wA0h, wA0l, wA1h, wA1l, s0part);
  k_p2<<<dim3(64, 4), 256, 0, stream>>>(data, conv1w, conv1b, p2);

  const float* s1o = s1init;
  float* outp = (float*)d_out;

  for (int t = 0; t < 10; t++) {
    int nb = t & 1;
    float* s1w = s1buf[nb];

    // conv0(s2_t from packed s2pk) + pool/argmax; s1_new = rho(p1 + fc^T(s0_t));
    // u = split(unpool(s1_old, idx)); s0 FC partials -> s0part buf[(t+1)&1]
    k_conv0F<<<dim3(64, 4, 2), 512, 0, stream>>>(s2pk,
                                                 wA0h, wA0l, conv0b,
                                                 s1o,
                                                 s0part + (t & 1) * 5120,
                                                 s0part + ((t + 1) & 1) * 5120,
                                                 fcb, fcw, s1w, u);
    // fused convT (tap-split waves): full-K sum + rho(p2+.)+split2 -> s2pk
    k_convTF<<<dim3(64, 2, 4), 512, 0, stream>>>(u, wA1h, wA1l, p2, s2pk);

    s1o = s1w;

    if (t == 6) {   // PRED_T snapshot: s0_7, s1_7, s2_7 = unpack(s2pk) -> d_out directly
      k_cTcomb<<<1536, 256, 0, stream>>>(s2pk, outp + 2098432,
                                         s1o, outp + 1574144,
                                         s0part + 5120, fcb, outp + 1573504);
    }
  }

  // final states: s0_10 (partials in buf[0]), s1_10, s2_10 -> d_out
  k_cTcomb<<<1536, 256, 0, stream>>>(s2pk, outp + 524928,
                                     s1o, outp + 640,
                                     s0part, fcb, outp + 0);
}

// Round 8
// 703.942 us; speedup vs baseline: 1.4933x; 1.0526x over previous
//
#include <hip/hip_runtime.h>

// convEP: 10-step EP relaxation, MFMA fp16 2-way-split convs (fp32-equivalent).
//   s0' = rho(fc(s1));  s1' = rho(pool(conv0(s2)) + fc^T(s0));  s2' = rho(p2 + convT(unpool(s1, idx1)))
// fp32 x = xh + 2^-12*xl' (fp16 planes, lo pre-scaled 2^12 to stay fp16-normal).
// MFMA 16x16x32_f16: A[m=l16][k=quad*8+j], B[k=quad*8+j][n=l16], C/D: col=l16, row=quad*4+reg.
// R21: conv0F gets the R20-convTF wave decomposition (24 MFMAs per 4-A-load group, proven 2x):
// grid (64 b, 4 cg, 4 yq) = 1024 blocks; waves = kc(2) x tg(4 taps {7,6,6,6}); nt=4 rows,
// mt=2 -> 6-7 iters/wave (was 25 with 12 MFMAs/group). 8 partials -> per-wave LDS C-slices
// [8][32][66] (67.6KB, 2 blk/CU) -> sum8 + bias in epilogue (fp32 reorder, same class as
// R20's safe reorder). Epilogue 1 window/thread; s0part 16 slots (cg4 x yq4).

typedef _Float16 half8 __attribute__((ext_vector_type(8)));
typedef _Float16 half2v __attribute__((ext_vector_type(2)));
typedef float f32x4 __attribute__((ext_vector_type(4)));
#define MFMA_F16(A, B, C) __builtin_amdgcn_mfma_f32_16x16x32_f16((A), (B), (C), 0, 0, 0)
#define LO_SCALE 2.44140625e-4f   // 2^-12

static __device__ __forceinline__ float rho_(float x) {
  return fminf(fmaxf(x, 0.0f), 1.0f);
}
static __device__ __forceinline__ void split2(float v, _Float16& h, _Float16& l) {
  if (fabsf(v) < 6.1035156e-5f) {
    h = (_Float16)0.f;
    l = (_Float16)(v * 4096.f);
  } else {
    h = (_Float16)v;
    l = (_Float16)((v - (float)h) * 4096.f);
  }
}

// ---------------- K0: one-time weight split+transpose + s0part init ----------------
// wA0[((tap*2+kc)*128 + co)*32 + cik] = conv0w[co][kc*32+cik][tap]
// wA1[((tap*4+c )*64  + o )*32 + cpk] = conv0w[(c*32+cpk)][o][tap]
// s0part: 2 bufs x [slot 16][b 64][10]; buf0 slot0 = -fcb (so rho(sum+fcb)=0 at t=0), rest 0.
__global__ __launch_bounds__(256) void k_wprep(
    const float* __restrict__ w0, const float* __restrict__ fcb,
    _Float16* __restrict__ wA0h, _Float16* __restrict__ wA0l,
    _Float16* __restrict__ wA1h, _Float16* __restrict__ wA1l,
    float* __restrict__ s0part) {
  int i = blockIdx.x * 256 + threadIdx.x;
  if (i >= 204800) return;
  if (i < 20480) {
    int k = i - (i / 10) * 10;
    s0part[i] = (i < 640) ? -fcb[k] : 0.f;
  }
  {
    int cik = i & 31, t1 = i >> 5;
    int co = t1 & 127, t2 = t1 >> 7;
    int ck = t2 & 1, tap = t2 >> 1;
    float v = w0[(co * 64 + ck * 32 + cik) * 25 + tap];
    _Float16 h, l; split2(v, h, l);
    wA0h[i] = h; wA0l[i] = l;
  }
  {
    int cpk = i & 31, t1 = i >> 5;
    int o = t1 & 63, t2 = t1 >> 6;
    int c = t2 & 3, tap = t2 >> 2;
    float v = w0[((c * 32 + cpk) * 64 + o) * 25 + tap];
    _Float16 h, l; split2(v, h, l);
    wA1h[i] = h; wA1l[i] = l;
  }
}

// ---------------- K1: p2 = maxpool2x2(conv2d(data, conv1_w) + conv1_b) (once, fp32) ----------------
__global__ __launch_bounds__(256) void k_p2(
    const float* __restrict__ data, const float* __restrict__ w,
    const float* __restrict__ bias, float* __restrict__ p2) {
  __shared__ float ld[3][36][36];
  __shared__ float lw[16][80];
  __shared__ float lb[16];
  int b = blockIdx.x, cg = blockIdx.y, tid = threadIdx.x;
  for (int i = tid; i < 3 * 36 * 36; i += 256) {
    int ci = i / 1296, rem = i % 1296, y = rem / 36, x = rem % 36;
    int gy = y - 2, gx = x - 2;
    float v = 0.f;
    if (gy >= 0 && gy < 32 && gx >= 0 && gx < 32)
      v = data[(b * 3 + ci) * 1024 + gy * 32 + gx];
    ld[ci][y][x] = v;
  }
  for (int i = tid; i < 16 * 75; i += 256) {
    int co = i / 75, k = i % 75;
    lw[co][k] = w[(cg * 16 + co) * 75 + k];
  }
  if (tid < 16) lb[tid] = bias[cg * 16 + tid];
  __syncthreads();
  int ph = tid >> 4, pw = tid & 15;
  int ry = 2 * ph, rx = 2 * pw;
  for (int co = 0; co < 16; co++) {
    float bv = lb[co];
    float a00 = bv, a01 = bv, a10 = bv, a11 = bv;
    for (int ci = 0; ci < 3; ci++) {
#pragma unroll
      for (int ky = 0; ky < 5; ky++) {
#pragma unroll
        for (int kx = 0; kx < 5; kx++) {
          float wv = lw[co][(ci * 5 + ky) * 5 + kx];
          a00 += wv * ld[ci][ry + ky][rx + kx];
          a01 += wv * ld[ci][ry + ky][rx + kx + 1];
          a10 += wv * ld[ci][ry + ky + 1][rx + kx];
          a11 += wv * ld[ci][ry + ky + 1][rx + kx + 1];
        }
      }
    }
    float m = fmaxf(fmaxf(a00, a01), fmaxf(a10, a11));
    p2[((b * 64 + cg * 16 + co) * 16 + ph) * 16 + pw] = m;
  }
}

// ---------------- K2: conv0 (y-quarter) + pool/argmax + s1 update + u write + s0 FC partial ----------------
// grid (64 b, 4 cg, 4 yq) = 1024 blocks, 512 thr = 8 waves = kc(2) x tg(4 taps {7,6,6,6}).
// Wave: nt=4 rows (the quarter) x mt=2 co-tiles, its tap subset, fixed kc. 6-7 iters,
// 4 A-loads (dbuf both planes) -> 24 MFMAs. Staging: 8-row halo slab of pre-split s2pk,
// x-zero-row at pos 128; plane = [129][72] halfs, lo at +9288 (37152 B).
// Combine: per-wave C-slices [8][32][66] f32 (67584 B) -> epilogue sum8 + bias.
// Epilogue: 1 window/thread (32 co x 16 win); s0 partial -> slot cg*4+yq (16 slots).
__global__ __launch_bounds__(512, 4) void k_conv0F(
    const unsigned* __restrict__ s2pk,
    const _Float16* __restrict__ wA0h, const _Float16* __restrict__ wA0l,
    const float* __restrict__ b0,
    const float* __restrict__ s1old,
    const float* __restrict__ s0prevPart, float* __restrict__ s0curPart,
    const float* __restrict__ fcb,
    const float* __restrict__ fcw, float* __restrict__ s1new,
    unsigned* __restrict__ u) {
  __shared__ __align__(16) _Float16 sm[33792];   // stage 37152 B; combine C 67584 B
  __shared__ float s0l[10];
  __shared__ float s0red[8][10];
  int b = blockIdx.x, cg = blockIdx.y, yq = blockIdx.z, tid = threadIdx.x;

  if (tid < 10) {   // s0_t = rho(sum of prev step's 16 slot partials + fcb); used in epilogue
    float s = 0.f;
#pragma unroll
    for (int sl = 0; sl < 16; sl++) s += s0prevPart[(sl * 64 + b) * 10 + tid];
    s0l[tid] = rho_(s + fcb[tid]);
  }

  // stage 8-row slab: pos = ly*16+lx (ly 0..7 -> gy = yq*4-2+ly), 64 ci; pre-split packed
  for (int i = tid; i < 8192; i += 512) {
    int ci = i >> 7, pos = i & 127;
    int ly = pos >> 4, lx = pos & 15;
    int gy = yq * 4 - 2 + ly;
    unsigned pk = 0u;
    if ((unsigned)gy < 16u) pk = s2pk[b * 16384 + ci * 256 + gy * 16 + lx];
    half2v hv = __builtin_bit_cast(half2v, pk);
    sm[pos * 72 + ci] = hv[0];
    sm[9288 + pos * 72 + ci] = hv[1];
  }
  // zero row (pos 128) in both planes: oob B-reads land here
  if (tid < 72) {
    sm[9216 + tid] = (_Float16)0.f;          // hi plane, pos 128
    sm[9288 + 9216 + tid] = (_Float16)0.f;   // lo plane, pos 128
  }
  __syncthreads();

  int lane = tid & 63, w = tid >> 6;
  int kc = w & 1, tg = w >> 1;
  int l16 = lane & 15, quad = lane >> 4;

  f32x4 acch[4][2], accl[4][2];   // [nt: 4 rows][mt]  (bias moved to epilogue)
#pragma unroll
  for (int nt = 0; nt < 4; nt++)
#pragma unroll
    for (int mt = 0; mt < 2; mt++) {
      f32x4 z; z[0] = 0.f; z[1] = 0.f; z[2] = 0.f; z[3] = 0.f;
      acch[nt][mt] = z; accl[nt][mt] = z;
    }

  const int bofs = kc * 32 + quad * 8;
  const int Abase = (kc * 128 + cg * 32 + l16) * 32 + quad * 8;   // + tap*8192 + mt*512
  const int tapLo = (tg == 0) ? 0 : 1 + 6 * tg;        // {0,7,13,19}
  const int tapEnd = tapLo + ((tg == 0) ? 7 : 6);

  half8 ahc[2], alc[2];
#pragma unroll
  for (int mt = 0; mt < 2; mt++) {
    ahc[mt] = *(const half8*)(wA0h + Abase + tapLo * 8192 + mt * 512);
    alc[mt] = *(const half8*)(wA0l + Abase + tapLo * 8192 + mt * 512);
  }

  for (int tap = tapLo; tap < tapEnd; tap++) {
    // prefetch next tap's A, both planes (full double-buffer)
    half8 ahn[2], aln[2];
    {
      int tn = (tap + 1 < tapEnd) ? tap + 1 : tap;
#pragma unroll
      for (int mt = 0; mt < 2; mt++) {
        ahn[mt] = *(const half8*)(wA0h + Abase + tn * 8192 + mt * 512);
        aln[mt] = *(const half8*)(wA0l + Abase + tn * 8192 + mt * 512);
      }
    }
    int ky = tap / 5, kx = tap - ky * 5;
    int ix = l16 + kx - 2;
    bool oob = ((unsigned)ix > 15u);
#pragma unroll
    for (int nt = 0; nt < 4; nt++) {
      int pos = (nt + ky) * 16 + ix;     // slab row nt+ky in 0..7 (y-halo staged)
      if (oob) pos = 128;                // zero row (broadcast read)
      const _Float16* bp = sm + pos * 72 + bofs;
      half8 bh = *(const half8*)bp;
      half8 bl = *(const half8*)(bp + 9288);
#pragma unroll
      for (int mt = 0; mt < 2; mt++) {
        acch[nt][mt] = MFMA_F16(ahc[mt], bh, acch[nt][mt]);
        accl[nt][mt] = MFMA_F16(alc[mt], bh, accl[nt][mt]);
        accl[nt][mt] = MFMA_F16(ahc[mt], bl, accl[nt][mt]);
      }
    }
#pragma unroll
    for (int mt = 0; mt < 2; mt++) { ahc[mt] = ahn[mt]; alc[mt] = aln[mt]; }
  }

  // combine: per-wave C-slice [w][co 32][66] (8*2112 floats = 67584 B, reuses slab)
  __syncthreads();
  float* C = (float*)sm;
  float* Cw = C + w * 2112;
#pragma unroll
  for (int nt = 0; nt < 4; nt++) {
    int pos = nt * 16 + l16;
#pragma unroll
    for (int mt = 0; mt < 2; mt++)
#pragma unroll
      for (int r = 0; r < 4; r++)
        Cw[(mt * 16 + quad * 4 + r) * 66 + pos] = acch[nt][mt][r] + LO_SCALE * accl[nt][mt][r];
  }
  __syncthreads();

  // epilogue: 1 window per thread (32 co x 16 windows; pooled rows yq*2, yq*2+1)
  {
    int co = tid >> 4, win = tid & 15;
    int phl = win >> 3, pw = win & 7;
    int p0 = phl * 32 + pw * 2;
    float bv = b0[cg * 32 + co];
    float v[4];
#pragma unroll
    for (int q = 0; q < 4; q++) {
      int ci = co * 66 + p0 + (q >> 1) * 16 + (q & 1);
      float s = C[ci]           + C[ci + 2112]  + C[ci + 4224]  + C[ci + 6336]
              + C[ci + 8448]    + C[ci + 10560] + C[ci + 12672] + C[ci + 14784];
      v[q] = s + bv;
    }
    float m0 = v[0]; int id = 0;
    if (v[1] > m0) { m0 = v[1]; id = 1; }
    if (v[2] > m0) { m0 = v[2]; id = 2; }
    if (v[3] > m0) { m0 = v[3]; id = 3; }
    int co_g = cg * 32 + co;
    int ph = yq * 2 + phl;
    int j = co_g * 64 + ph * 8 + pw;
    float sv = s1old[b * 8192 + j];
    float a = m0;
    float pacc[10];
#pragma unroll
    for (int k = 0; k < 10; k++) {
      float wv = fcw[k * 8192 + j];
      a += s0l[k] * wv;
      pacc[k] = sv * wv;       // s0 FC partial (reuses the fcw load)
    }
    s1new[b * 8192 + j] = rho_(a);
    _Float16 hh, hl; split2(sv, hh, hl);
    half2v hv; hv[0] = hh; hv[1] = hl;
    unsigned pk = __builtin_bit_cast(unsigned, hv);
    int bu = (b * 256 + ph * 32 + pw * 2) * 128 + co_g;   // u32 units: [b][pos 256][cp 128]
    u[bu]        = (id == 0) ? pk : 0u;
    u[bu + 128]  = (id == 1) ? pk : 0u;
    u[bu + 2048] = (id == 2) ? pk : 0u;
    u[bu + 2176] = (id == 3) ? pk : 0u;

    // s0 partial: wave butterfly -> LDS -> 10 plain stores per block (no atomics)
    int lane2 = tid & 63, w2 = tid >> 6;
#pragma unroll
    for (int k = 0; k < 10; k++) {
      float vv = pacc[k];
#pragma unroll
      for (int off = 32; off > 0; off >>= 1) vv += __shfl_xor(vv, off);
      if (lane2 == 0) s0red[w2][k] = vv;
    }
  }
  __syncthreads();
  if (tid < 10) {
    float s = s0red[0][tid] + s0red[1][tid] + s0red[2][tid] + s0red[3][tid]
            + s0red[4][tid] + s0red[5][tid] + s0red[6][tid] + s0red[7][tid];
    s0curPart[((cg * 4 + yq) * 64 + b) * 10 + tid] = s;
  }
}

// ---------------- K3: FUSED convT: full-K GEMM + rho(p2+.)+split2 -> s2pk ----------------
// R20: wave = kc(2 cp-half) x tg(4 tap-group {7,6,6,6}); nt=4 rows (whole y-quarter).
// Per iter (tap,cs): 4 A-loads (double-buffered both planes) -> 24 MFMAs. 12-14 iters.
// grid (64 b, 2 oh, 4 yq) = 512 blocks. Stage: 8-row u halo slab, x-zero-row at pos 128.
// LDS 70176 B -> 2 blk/CU. 8 partials -> per-wave C-slices [8][32][66] (67.6KB, one
// parallel write) -> sum8 + rho(p2+.) + split2 -> s2pk. No P1, no atomics, no fences.
__global__ __launch_bounds__(512, 4) void k_convTF(
    const unsigned* __restrict__ u,
    const _Float16* __restrict__ wA1h, const _Float16* __restrict__ wA1l,
    const float* __restrict__ p2, unsigned* __restrict__ s2pk) {
  __shared__ __align__(16) _Float16 sm[35088];   // 2 planes x [pos 129][136] = 70176 B
  int b = blockIdx.x, oh = blockIdx.y, yq = blockIdx.z, tid = threadIdx.x;

  // stage: 8 rows x 16 x x 128 cp of packed u -> two planes
  for (int i = tid; i < 16384; i += 512) {
    int cp = i & 127, pl = i >> 7;       // pl 0..127
    int ly = pl >> 4, lx = pl & 15;
    int gy = yq * 4 - 2 + ly;
    unsigned pk = 0u;
    if ((unsigned)gy < 16u) pk = u[b * 32768 + (gy * 16 + lx) * 128 + cp];
    half2v hv = __builtin_bit_cast(half2v, pk);
    sm[pl * 136 + cp] = hv[0];
    sm[17544 + pl * 136 + cp] = hv[1];
  }
  // zero row (pos 128) both planes: 136 halfs = 68 u32 each
  if (tid < 68) {
    ((unsigned*)sm)[8704 + tid] = 0u;            // 128*136/2
    ((unsigned*)sm)[8772 + 8704 + tid] = 0u;     // + plane offset 17544/2
  }
  __syncthreads();

  int lane = tid & 63, w = tid >> 6;
  int kc = w & 1, tg = w >> 1;
  int l16 = lane & 15, quad = lane >> 4;

  f32x4 acch[4][2], accl[4][2];   // [nt: 4 rows][mt]
#pragma unroll
  for (int nt = 0; nt < 4; nt++)
#pragma unroll
    for (int mt = 0; mt < 2; mt++) {
      f32x4 z; z[0] = 0.f; z[1] = 0.f; z[2] = 0.f; z[3] = 0.f;
      acch[nt][mt] = z; accl[nt][mt] = z;
    }

  const int Aoff = (oh * 32 + l16) * 32 + quad * 8;
  const int bofs = kc * 64 + quad * 8;
  const int tapLo = (tg == 0) ? 0 : 1 + 6 * tg;       // {0,7,13,19}
  const int itBeg = tapLo * 2;
  const int itEnd = (tapLo + ((tg == 0) ? 7 : 6)) * 2;

  half8 ahc[2], alc[2];
  {
    int Ab = (tapLo * 4 + kc * 2) * 2048;
#pragma unroll
    for (int mt = 0; mt < 2; mt++) {
      ahc[mt] = *(const half8*)(wA1h + Ab + Aoff + mt * 512);
      alc[mt] = *(const half8*)(wA1l + Ab + Aoff + mt * 512);
    }
  }

  for (int it = itBeg; it < itEnd; it++) {
    // prefetch next iter's A, both planes (full double-buffer)
    half8 ahn[2], aln[2];
    {
      int itn = (it + 1 < itEnd) ? it + 1 : it;
      int Abn = ((itn >> 1) * 4 + kc * 2 + (itn & 1)) * 2048;
#pragma unroll
      for (int mt = 0; mt < 2; mt++) {
        ahn[mt] = *(const half8*)(wA1h + Abn + Aoff + mt * 512);
        aln[mt] = *(const half8*)(wA1l + Abn + Aoff + mt * 512);
      }
    }
    int tap = it >> 1, cs = it & 1;
    int ky = tap / 5, kx = tap - ky * 5;
    int ix = l16 + 2 - kx;
    bool oob = ((unsigned)ix > 15u);
#pragma unroll
    for (int nt = 0; nt < 4; nt++) {
      int pos = (nt + 4 - ky) * 16 + ix;   // slab row in 0..7 (y-halo staged, never oob)
      if (oob) pos = 128;                  // zero row (broadcast read)
      const _Float16* bp = sm + pos * 136 + bofs + cs * 32;
      half8 bh = *(const half8*)bp;
      half8 bl = *(const half8*)(bp + 17544);
#pragma unroll
      for (int mt = 0; mt < 2; mt++) {
        acch[nt][mt] = MFMA_F16(ahc[mt], bh, acch[nt][mt]);
        accl[nt][mt] = MFMA_F16(alc[mt], bh, accl[nt][mt]);
        accl[nt][mt] = MFMA_F16(ahc[mt], bl, accl[nt][mt]);
      }
    }
#pragma unroll
    for (int mt = 0; mt < 2; mt++) { ahc[mt] = ahn[mt]; alc[mt] = aln[mt]; }
  }

  // combine: per-wave C-slice [w][o 32][66] (8*2112 floats = 67584 B, reuses slab)
  __syncthreads();
  float* C = (float*)sm;
  float* Cw = C + w * 2112;
#pragma unroll
  for (int nt = 0; nt < 4; nt++) {
    int pos = nt * 16 + l16;
#pragma unroll
    for (int mt = 0; mt < 2; mt++)
#pragma unroll
      for (int r = 0; r < 4; r++)
        Cw[(mt * 16 + quad * 4 + r) * 66 + pos] = acch[nt][mt][r] + LO_SCALE * accl[nt][mt][r];
  }
  __syncthreads();

  // epilogue: s2 = rho(p2 + sum8), split2, pack -> s2pk (32 o x 64 pos)
  int gbase = b * 16384 + oh * 8192 + yq * 64;
  for (int m = tid; m < 2048; m += 512) {
    int o = m >> 6, pos = m & 63;        // pos = row*16 + x
    int ci = o * 66 + pos;
    float s = C[ci]          + C[ci + 2112]  + C[ci + 4224]  + C[ci + 6336]
            + C[ci + 8448]   + C[ci + 10560] + C[ci + 12672] + C[ci + 14784];
    int gi = gbase + o * 256 + pos;
    float v = rho_(p2[gi] + s);
    _Float16 h, l; split2(v, h, l);
    half2v hv; hv[0] = h; hv[1] = l;
    s2pk[gi] = __builtin_bit_cast(unsigned, hv);
  }
}

// ---------------- K3b: s2 unpack + s1 copy + s0 finalize (t=6 snapshot, t=9 final) ----------------
// blocks 0..1023: s2 = unpack(s2pk) (+ first 640 lanes: s0 = rho(sum 16 partials + fcb));
// blocks 1024..1535: s1 float4 copy.
__global__ __launch_bounds__(256) void k_cTcomb(
    const unsigned* __restrict__ s2pk, float* __restrict__ out_s2,
    const float* __restrict__ s1src, float* __restrict__ out_s1,
    const float* __restrict__ s0part, const float* __restrict__ fcb,
    float* __restrict__ out_s0) {
  int blk = blockIdx.x, tid = threadIdx.x;
  if (blk < 1024) {
    int i = blk * 256 + tid;   // over 262144 uint4s
    uint4 pk = ((const uint4*)s2pk)[i];
    float4 o;
    half2v h0 = __builtin_bit_cast(half2v, pk.x);
    half2v h1 = __builtin_bit_cast(half2v, pk.y);
    half2v h2 = __builtin_bit_cast(half2v, pk.z);
    half2v h3 = __builtin_bit_cast(half2v, pk.w);
    o.x = (float)h0[0] + LO_SCALE * (float)h0[1];
    o.y = (float)h1[0] + LO_SCALE * (float)h1[1];
    o.z = (float)h2[0] + LO_SCALE * (float)h2[1];
    o.w = (float)h3[0] + LO_SCALE * (float)h3[1];
    ((float4*)out_s2)[i] = o;
    if (i < 640) {
      int bb = i / 10, k = i - bb * 10;
      float s = 0.f;
#pragma unroll
      for (int sl = 0; sl < 16; sl++) s += s0part[(sl * 64 + bb) * 10 + k];
      out_s0[i] = rho_(s + fcb[k]);
    }
  } else {
    int i2 = (blk - 1024) * 256 + tid;   // over 131072 float4s (2 MB)
    ((float4*)out_s1)[i2] = ((const float4*)s1src)[i2];
  }
}

extern "C" void kernel_launch(void* const* d_in, const int* in_sizes, int n_in,
                              void* d_out, int out_size, void* d_ws, size_t ws_size,
                              hipStream_t stream) {
  const float* data   = (const float*)d_in[0];
  const float* s0init = (const float*)d_in[1];   // zeros
  const float* s1init = (const float*)d_in[2];   // zeros
  const float* s2init = (const float*)d_in[3];   // zeros (t=0 conv0 input)
  const float* conv0w = (const float*)d_in[4];
  const float* conv0b = (const float*)d_in[5];
  const float* conv1w = (const float*)d_in[6];
  const float* conv1b = (const float*)d_in[7];
  const float* fcw    = (const float*)d_in[8];
  const float* fcb    = (const float*)d_in[9];
  (void)s0init; (void)s2init;

  // workspace (~22 MB of 256 MB)
  float* p = (float*)d_ws;
  float* s0part = p;                         p += 20480;     // 2 bufs x [slot 16][b 64][10]
  float* s1buf[2] = {p, p + 524288};         p += 1048576;
  float* p2 = p;                             p += 1048576;
  unsigned* u = (unsigned*)p;                p += 2097152;   // packed hi|lo [b][pos 256][cp 128]
  unsigned* s2pk = (unsigned*)p;             p += 1048576;   // packed split s2 [b][ci 64][16][16]
  _Float16* hq = (_Float16*)p;
  _Float16* wA0h = hq;                       hq += 204800;
  _Float16* wA0l = hq;                       hq += 204800;
  _Float16* wA1h = hq;                       hq += 204800;
  _Float16* wA1l = hq;                       hq += 204800;

  hipMemsetAsync(s2pk, 0, 1048576 * sizeof(unsigned), stream);   // t=0: s2 = 0 (packed split(0)=0)
  k_wprep<<<800, 256, 0, stream>>>(conv0w, fcb, wA0h, wA0l, wA1h, wA1l, s0part);
  k_p2<<<dim3(64, 4), 256, 0, stream>>>(data, conv1w, conv1b, p2);

  const float* s1o = s1init;
  float* outp = (float*)d_out;

  for (int t = 0; t < 10; t++) {
    int nb = t & 1;
    float* s1w = s1buf[nb];

    // conv0(s2_t from packed s2pk) + pool/argmax; s1_new = rho(p1 + fc^T(s0_t));
    // u = split(unpool(s1_old, idx)); s0 FC partials -> s0part buf[(t+1)&1]
    k_conv0F<<<dim3(64, 4, 4), 512, 0, stream>>>(s2pk,
                                                 wA0h, wA0l, conv0b,
                                                 s1o,
                                                 s0part + (t & 1) * 10240,
                                                 s0part + ((t + 1) & 1) * 10240,
                                                 fcb, fcw, s1w, u);
    // fused convT (tap-split waves): full-K sum + rho(p2+.)+split2 -> s2pk
    k_convTF<<<dim3(64, 2, 4), 512, 0, stream>>>(u, wA1h, wA1l, p2, s2pk);

    s1o = s1w;

    if (t == 6) {   // PRED_T snapshot: s0_7, s1_7, s2_7 = unpack(s2pk) -> d_out directly
      k_cTcomb<<<1536, 256, 0, stream>>>(s2pk, outp + 2098432,
                                         s1o, outp + 1574144,
                                         s0part + 10240, fcb, outp + 1573504);
    }
  }

  // final states: s0_10 (partials in buf[0]), s1_10, s2_10 -> d_out
  k_cTcomb<<<1536, 256, 0, stream>>>(s2pk, outp + 524928,
                                     s1o, outp + 640,
                                     s0part, fcb, outp + 0);
}